// Round 13
// baseline (362.235 us; speedup 1.0000x reference)
//
#include <hip/hip_runtime.h>
#include <hip/hip_bf16.h>
#include <type_traits>

#define B_ 8
#define L_ 8192
#define D_ 512
#define H_ 8
#define KD_ 64
#define W_ 128
#define C_ 64
#define M_ (B_ * L_)   // 65536
#define HK_ 512

typedef __bf16 bf16_t;
typedef __bf16 bf16x8 __attribute__((ext_vector_type(8)));
typedef float f32x4 __attribute__((ext_vector_type(4)));

#define GLOAD16(gp, lp)                                                        \
  __builtin_amdgcn_global_load_lds(                                            \
      (const __attribute__((address_space(1))) unsigned int*)(gp),             \
      (__attribute__((address_space(3))) unsigned int*)(lp), 16, 0, 0)

#define WAIT_LGKM0()                                                           \
  do {                                                                         \
    asm volatile("s_waitcnt lgkmcnt(0)" ::: "memory");                         \
    __builtin_amdgcn_sched_barrier(0);                                         \
  } while (0)

#define MFMA16(AF, BF, ACC, OFF)                                               \
  do {                                                                         \
    __builtin_amdgcn_s_setprio(1);                                             \
    _Pragma("unroll") for (int i_ = 0; i_ < 4; i_++)                           \
        _Pragma("unroll") for (int j_ = 0; j_ < 4; j_++)                       \
            ACC[i_ + OFF][j_] = __builtin_amdgcn_mfma_f32_16x16x32_bf16(       \
                AF[i_], BF[j_], ACC[i_ + OFF][j_], 0, 0, 0);                   \
    __builtin_amdgcn_s_setprio(0);                                             \
  } while (0)

// ---------------------------------------------------------------------------
// Prep (coalesced LDS-tile transpose, proven r9-r12):
// wt[mat][n][d] = W[mat][d][n] * scale.
// ---------------------------------------------------------------------------
__global__ void prep_weights_kernel(const float* __restrict__ Wq,
                                    const float* __restrict__ Wk,
                                    const float* __restrict__ Wv,
                                    const float* __restrict__ Wo,
                                    bf16_t* __restrict__ wt) {
  __shared__ float t[64][65];
  const int tid = threadIdx.x;
  const int mat = blockIdx.z;
  const float* src = (mat == 0) ? Wq : (mat == 1) ? Wk : (mat == 2) ? Wv : Wo;
  const float scale = (mat == 0) ? 0.125f : 1.0f;  // 1/sqrt(64) folded into Wq
  const int d0 = blockIdx.x * 64, n0 = blockIdx.y * 64;
  const int c = tid & 63, rb = tid >> 6;
#pragma unroll
  for (int i = 0; i < 16; i++) {
    const int r = i * 4 + rb;
    t[r][c] = src[(size_t)(d0 + r) * 512 + n0 + c];
  }
  __syncthreads();
#pragma unroll
  for (int i = 0; i < 16; i++) {
    const int n = i * 4 + rb;
    wt[((size_t)mat * 512 + n0 + n) * 512 + d0 + c] = (bf16_t)(t[c][n] * scale);
  }
}

// ---------------------------------------------------------------------------
// Convert Xq / Xkv fp32 -> bf16 (streaming, at HBM floor; proven r2-r7)
// ---------------------------------------------------------------------------
__global__ void cvt_x_kernel(const float* __restrict__ xq,
                             const float* __restrict__ xkv,
                             bf16_t* __restrict__ oq,
                             bf16_t* __restrict__ okv) {
  const float* src = blockIdx.y ? xkv : xq;
  bf16_t* dst = blockIdx.y ? okv : oq;
  const size_t e = ((size_t)blockIdx.x * blockDim.x + threadIdx.x) * 8;
  float4 a = *reinterpret_cast<const float4*>(src + e);
  float4 b = *reinterpret_cast<const float4*>(src + e + 4);
  bf16x8 o;
  o[0] = (bf16_t)a.x; o[1] = (bf16_t)a.y; o[2] = (bf16_t)a.z; o[3] = (bf16_t)a.w;
  o[4] = (bf16_t)b.x; o[5] = (bf16_t)b.y; o[6] = (bf16_t)b.z; o[7] = (bf16_t)b.w;
  *reinterpret_cast<bf16x8*>(dst + e) = o;
}

// ---------------------------------------------------------------------------
// Fragment read, [256 rows][32 bf16] region (64 B rows), proven balanced
// swizzle (0 conflicts measured): LDS[row][p] = global[row][p ^ ((row>>1)&3)].
// ---------------------------------------------------------------------------
__device__ __forceinline__ bf16x8 rdfrag(const bf16_t* region, int rowbase,
                                         int lane) {
  const int fr = lane & 15;
  const int fs = (lane >> 4) ^ ((lane >> 1) & 3);
  return *reinterpret_cast<const bf16x8*>(region + (rowbase + fr) * 32 + fs * 8);
}

// ---------------------------------------------------------------------------
// 256x256 8-phase GEMM (proven r7: 132 us QKV, 0 conflicts): all-bf16, K=512.
//   512 threads = 8 waves (2M x 4N), BK=64, LDS 128 KB double-buffered,
//   counted vmcnt(6), both-sides swizzle, T1 XCD-bijective grid.
//   NTILE n-tiles: seg=mx>>1 picks A0->C0 / A1->C1,C2 (fused QKV); NTILE=2
//   uses seg 0 only (O-projection).
// ---------------------------------------------------------------------------
template <typename OT, int NTILE>
__global__ __launch_bounds__(512, 2)
void gemm256(const bf16_t* __restrict__ A0, const bf16_t* __restrict__ A1,
             const bf16_t* __restrict__ BT,
             OT* __restrict__ C0, OT* __restrict__ C1, OT* __restrict__ C2) {
  __shared__ __align__(16) bf16_t lds[65536];  // 128 KiB

  constexpr int NB = NTILE * 256;
  const int bid = blockIdx.x;
  const int swz = (bid & 7) * (NB / 8) + (bid >> 3);
  const int my = swz / NTILE;
  const int mx = swz - my * NTILE;
  const int m0 = my * 256;
  const int seg = mx >> 1;
  const int ncol0 = (mx & 1) * 256;
  const int nB0 = mx * 256;

  const bf16_t* const A = (seg == 0) ? A0 : A1;
  OT* const outp = (seg == 0) ? C0 : (seg == 1) ? C1 : C2;

  const int tid = threadIdx.x;
  const int lane = tid & 63;
  const int wid = tid >> 6;
  const int wmB = (wid >> 2) * 128;
  const int wnB = (wid & 3) * 64;

  const int sr0 = tid >> 2;
  const int sgs = (tid & 3) ^ ((sr0 >> 1) & 3);
  const bf16_t* const Agb = A + ((size_t)m0 + sr0) * 512 + sgs * 8;
  const bf16_t* const Bgb = BT + ((size_t)nB0 + sr0) * 512 + sgs * 8;

  auto stage = [&](int tile, int mat, int kh) {
    if (tile >= 8) return;
    bf16_t* reg = lds + ((tile & 1) * 4 + mat * 2 + kh) * 8192;
    const bf16_t* g0 = (mat == 0 ? Agb : Bgb) + tile * 64 + kh * 32;
    char* lp = (char*)reg + wid * 1024;
    GLOAD16(g0, lp);
    GLOAD16(g0 + (size_t)128 * 512, lp + 8192);
  };

  f32x4 acc[8][4] = {};
  bf16x8 a0[4], a1[4], a2[4], a3[4], b0[4], b2[4];

  // prologue: tile0 fully + tile1 {Bkh0, Akh0, Bkh1}  (7 half-tiles)
  stage(0, 0, 0); stage(0, 1, 0); stage(0, 0, 1); stage(0, 1, 1);
  stage(1, 1, 0); stage(1, 0, 0); stage(1, 1, 1);
  asm volatile("s_waitcnt vmcnt(6)" ::: "memory");  // tile0 landed
  __builtin_amdgcn_s_barrier();

  for (int t = 0; t < 8; ++t) {
    const int p = t & 1;
    const bf16_t* Ap0 = lds + (p * 4 + 0) * 8192;
    const bf16_t* Ap1 = lds + (p * 4 + 1) * 8192;
    const bf16_t* Bp0 = lds + (p * 4 + 2) * 8192;
    const bf16_t* Bp1 = lds + (p * 4 + 3) * 8192;

    // ph0: RD A[kh0]m0-3 + B[kh0]; ST A(t+1)kh1; MFMA tail t-1
#pragma unroll
    for (int q = 0; q < 4; q++) a0[q] = rdfrag(Ap0, wmB + q * 16, lane);
#pragma unroll
    for (int q = 0; q < 4; q++) b0[q] = rdfrag(Bp0, wnB + q * 16, lane);
    stage(t + 1, 0, 1);
    __builtin_amdgcn_s_barrier();
    WAIT_LGKM0();
    if (t > 0) MFMA16(a3, b2, acc, 4);
    __builtin_amdgcn_s_barrier();

    // ph1: RD A[kh0]m4-7; ST B(t+2)kh0; MFMA m0-3 x kh0
#pragma unroll
    for (int q = 0; q < 4; q++) a1[q] = rdfrag(Ap0, wmB + 64 + q * 16, lane);
    stage(t + 2, 1, 0);
    __builtin_amdgcn_s_barrier();
    WAIT_LGKM0();
    MFMA16(a0, b0, acc, 0);
    __builtin_amdgcn_s_barrier();

    // ph2: RD A[kh1]m0-3 + B[kh1]; ST A(t+2)kh0; MFMA m4-7 x kh0
#pragma unroll
    for (int q = 0; q < 4; q++) a2[q] = rdfrag(Ap1, wmB + q * 16, lane);
#pragma unroll
    for (int q = 0; q < 4; q++) b2[q] = rdfrag(Bp1, wnB + q * 16, lane);
    stage(t + 2, 0, 0);
    __builtin_amdgcn_s_barrier();
    WAIT_LGKM0();
    MFMA16(a1, b0, acc, 4);
    __builtin_amdgcn_s_barrier();

    // ph3: RD A[kh1]m4-7; ST B(t+2)kh1; MFMA m0-3 x kh1; vmcnt gate
#pragma unroll
    for (int q = 0; q < 4; q++) a3[q] = rdfrag(Ap1, wmB + 64 + q * 16, lane);
    stage(t + 2, 1, 1);
    __builtin_amdgcn_s_barrier();
    WAIT_LGKM0();
    MFMA16(a2, b2, acc, 0);
    if (t < 6) {
      asm volatile("s_waitcnt vmcnt(6)" ::: "memory");  // tile t+1 landed
    } else {
      asm volatile("s_waitcnt vmcnt(0)" ::: "memory");  // tail drain
    }
    __builtin_amdgcn_s_barrier();
  }

  MFMA16(a3, b2, acc, 4);  // tile7 m4-7 x kh1

  const int crow = (lane >> 4) * 4;
  const int ccol = lane & 15;
#pragma unroll
  for (int i = 0; i < 8; i++) {
#pragma unroll
    for (int j = 0; j < 4; j++) {
      const int gm = m0 + wmB + i * 16 + crow;
      const int gn = ncol0 + wnB + j * 16 + ccol;
#pragma unroll
      for (int jj = 0; jj < 4; jj++) {
        const float vv = acc[i][j][jj];
        if constexpr (std::is_same<OT, float>::value)
          outp[(size_t)(gm + jj) * 512 + gn] = vv;
        else
          outp[(size_t)(gm + jj) * 512 + gn] = (bf16_t)vv;
      }
    }
  }
}

// ---------------------------------------------------------------------------
// Attention (proven r12): one block per (h, c, b), XCD-swizzled, 4 waves x
// 32 rows, T5 setprio around MFMA clusters. CLS key via VALU dot + rank-1.
// ---------------------------------------------------------------------------
__global__ __launch_bounds__(256, 3)
void attn_kernel(const bf16_t* __restrict__ q, const bf16_t* __restrict__ k,
                 const bf16_t* __restrict__ v, bf16_t* __restrict__ ctx) {
  const int bid = blockIdx.x;                      // 4096 blocks
  const int swz = (bid & 7) * 512 + (bid >> 3);    // 4096 % 8 == 0
  const int h = swz & 7;
  const int cb = swz >> 3;
  const int c = cb & 63;
  const int b = cb >> 6;

  const int tid = threadIdx.x;
  const int lane = tid & 63;
  const int w = tid >> 6;
  const int cl = lane & 15;
  const int g = lane >> 4;

  __shared__ bf16_t vT[64][136];    // V^T: [kdim][m]
  __shared__ bf16_t pL[128][136];   // normalized P (bf16)
  __shared__ float scl[128];        // cls score, then normalized cls prob
  __shared__ bf16_t kcls[64];
  __shared__ bf16_t vcls[64];

  const size_t headoff = (size_t)h * KD_;
  const size_t rowbase = (size_t)b * L_ + (size_t)c * W_;

  if (tid < 64) {
    kcls[tid] = k[(size_t)b * L_ * HK_ + headoff + tid];
    vcls[tid] = v[(size_t)b * L_ * HK_ + headoff + tid];
  }
  {
    const int m = tid >> 1;
    const int kd0 = (tid & 1) * 32;
    const bf16_t* vp = v + (rowbase + m) * HK_ + headoff + kd0;
#pragma unroll
    for (int i = 0; i < 4; i++) {
      bf16x8 t8 = *reinterpret_cast<const bf16x8*>(vp + i * 8);
#pragma unroll
      for (int j = 0; j < 8; j++) vT[kd0 + i * 8 + j][m] = t8[j];
    }
  }

  bf16x8 qf[2][2];
#pragma unroll
  for (int rt = 0; rt < 2; rt++)
#pragma unroll
    for (int kk = 0; kk < 2; kk++) {
      const size_t row = rowbase + w * 32 + rt * 16 + cl;
      qf[rt][kk] = *reinterpret_cast<const bf16x8*>(&q[row * HK_ + headoff + kk * 32 + g * 8]);
    }

  f32x4 sacc[2][8] = {};
#pragma unroll
  for (int ct = 0; ct < 8; ct++) {
    bf16x8 kf[2];
#pragma unroll
    for (int kk = 0; kk < 2; kk++) {
      const size_t rowm = rowbase + ct * 16 + cl;
      kf[kk] = *reinterpret_cast<const bf16x8*>(&k[rowm * HK_ + headoff + kk * 32 + g * 8]);
    }
    __builtin_amdgcn_s_setprio(1);
#pragma unroll
    for (int rt = 0; rt < 2; rt++)
#pragma unroll
      for (int kk = 0; kk < 2; kk++)
        sacc[rt][ct] = __builtin_amdgcn_mfma_f32_16x16x32_bf16(qf[rt][kk], kf[kk], sacc[rt][ct], 0, 0, 0);
    __builtin_amdgcn_s_setprio(0);
  }

  __syncthreads();

#pragma unroll
  for (int rt = 0; rt < 2; rt++) {
    float part = 0.f;
#pragma unroll
    for (int kk = 0; kk < 2; kk++)
#pragma unroll
      for (int j = 0; j < 8; j++)
        part += (float)qf[rt][kk][j] * (float)kcls[kk * 32 + g * 8 + j];
    part += __shfl_xor(part, 16);
    part += __shfl_xor(part, 32);
    if (g == 0) scl[w * 32 + rt * 16 + cl] = part;
  }

  float invd[2][4];
#pragma unroll
  for (int rt = 0; rt < 2; rt++) {
#pragma unroll
    for (int jj = 0; jj < 4; jj++) {
      float mx = sacc[rt][0][jj];
#pragma unroll
      for (int ct = 1; ct < 8; ct++) mx = fmaxf(mx, sacc[rt][ct][jj]);
#pragma unroll
      for (int d = 1; d < 16; d <<= 1) mx = fmaxf(mx, __shfl_xor(mx, d));
      const float sc = scl[w * 32 + rt * 16 + g * 4 + jj];
      mx = fmaxf(mx, sc);
      float sum = 0.f;
#pragma unroll
      for (int ct = 0; ct < 8; ct++) {
        const float e = __expf(sacc[rt][ct][jj] - mx);
        sacc[rt][ct][jj] = e;
        sum += e;
      }
#pragma unroll
      for (int d = 1; d < 16; d <<= 1) sum += __shfl_xor(sum, d);
      const float pc = __expf(sc - mx);
      sum += pc;
      const float inv = 1.0f / sum;
      invd[rt][jj] = inv;
      if (cl == 0) scl[w * 32 + rt * 16 + g * 4 + jj] = pc * inv;
    }
  }

#pragma unroll
  for (int rt = 0; rt < 2; rt++)
#pragma unroll
    for (int jj = 0; jj < 4; jj++) {
      const int row = w * 32 + rt * 16 + g * 4 + jj;
#pragma unroll
      for (int ct = 0; ct < 8; ct++)
        pL[row][ct * 16 + cl] = (bf16_t)(sacc[rt][ct][jj] * invd[rt][jj]);
    }
  __syncthreads();

  f32x4 cacc[2][4] = {};
#pragma unroll
  for (int kk = 0; kk < 4; kk++) {
    bf16x8 vf[4];
#pragma unroll
    for (int c2 = 0; c2 < 4; c2++)
      vf[c2] = *reinterpret_cast<const bf16x8*>(&vT[c2 * 16 + cl][kk * 32 + g * 8]);
    __builtin_amdgcn_s_setprio(1);
#pragma unroll
    for (int rt = 0; rt < 2; rt++) {
      const bf16x8 pf = *reinterpret_cast<const bf16x8*>(&pL[w * 32 + rt * 16 + cl][kk * 32 + g * 8]);
#pragma unroll
      for (int c2 = 0; c2 < 4; c2++)
        cacc[rt][c2] = __builtin_amdgcn_mfma_f32_16x16x32_bf16(pf, vf[c2], cacc[rt][c2], 0, 0, 0);
    }
    __builtin_amdgcn_s_setprio(0);
  }

#pragma unroll
  for (int rt = 0; rt < 2; rt++)
#pragma unroll
    for (int c2 = 0; c2 < 4; c2++)
#pragma unroll
      for (int jj = 0; jj < 4; jj++) {
        const int row = w * 32 + rt * 16 + g * 4 + jj;
        const int kd = c2 * 16 + cl;
        const float val = cacc[rt][c2][jj] + scl[row] * (float)vcls[kd];
        ctx[(rowbase + row) * HK_ + headoff + kd] = (bf16_t)val;
      }
}

// ---------------------------------------------------------------------------
extern "C" void kernel_launch(void* const* d_in, const int* in_sizes, int n_in,
                              void* d_out, int out_size, void* d_ws, size_t ws_size,
                              hipStream_t stream) {
  const float* Xq = (const float*)d_in[0];
  const float* Xkv = (const float*)d_in[1];
  const float* Wq = (const float*)d_in[2];
  const float* Wk = (const float*)d_in[3];
  const float* Wv = (const float*)d_in[4];
  const float* Wo = (const float*)d_in[5];
  float* out = (float*)d_out;

  char* ws = (char*)d_ws;
  bf16_t* wT = (bf16_t*)ws;                                   // 4 x 512 x 512 bf16
  size_t off = (size_t)4 * 512 * 512 * sizeof(bf16_t);        // 2 MiB
  bf16_t* xqb  = (bf16_t*)(ws + off); off += (size_t)M_ * D_ * 2;
  bf16_t* xkvb = (bf16_t*)(ws + off); off += (size_t)M_ * D_ * 2;
  bf16_t* qb = (bf16_t*)(ws + off); off += (size_t)M_ * HK_ * 2;
  bf16_t* kb = (bf16_t*)(ws + off); off += (size_t)M_ * HK_ * 2;
  bf16_t* vb = (bf16_t*)(ws + off);
  bf16_t* ctxb = xqb;  // xqb dead after QKV projection; reuse for ctx

  bf16_t* wTqkv = wT;                      // q|k|v stacked: 1536 rows
  bf16_t* wTo = wT + (size_t)3 * 512 * 512;

  prep_weights_kernel<<<dim3(8, 8, 4), 256, 0, stream>>>(Wq, Wk, Wv, Wo, wT);
  cvt_x_kernel<<<dim3(M_ * D_ / 8 / 256, 2), 256, 0, stream>>>(Xq, Xkv, xqb, xkvb);

  // Fused Q+K+V projections: 6 n-tiles (2 per output) x 256 m-panels
  gemm256<bf16_t, 6><<<dim3(6 * (M_ / 256)), 512, 0, stream>>>(
      xqb, xkvb, wTqkv, qb, kb, vb);

  attn_kernel<<<dim3(H_ * C_ * B_), 256, 0, stream>>>(qb, kb, vb, ctxb);

  // Output projection: ctx [M][512] bf16 @ WoT -> out fp32
  gemm256<float, 2><<<dim3(2 * (M_ / 256)), 512, 0, stream>>>(
      ctxb, ctxb, wTo, out, out, out);
}

// Round 14
// 357.502 us; speedup vs baseline: 1.0132x; 1.0132x over previous
//
#include <hip/hip_runtime.h>
#include <hip/hip_bf16.h>
#include <type_traits>

#define B_ 8
#define L_ 8192
#define D_ 512
#define H_ 8
#define KD_ 64
#define W_ 128
#define C_ 64
#define M_ (B_ * L_)   // 65536
#define HK_ 512

typedef __bf16 bf16_t;
typedef __bf16 bf16x8 __attribute__((ext_vector_type(8)));
typedef float f32x4 __attribute__((ext_vector_type(4)));

#define GLOAD16(gp, lp)                                                        \
  __builtin_amdgcn_global_load_lds(                                            \
      (const __attribute__((address_space(1))) unsigned int*)(gp),             \
      (__attribute__((address_space(3))) unsigned int*)(lp), 16, 0, 0)

#define WAIT_LGKM0()                                                           \
  do {                                                                         \
    asm volatile("s_waitcnt lgkmcnt(0)" ::: "memory");                         \
    __builtin_amdgcn_sched_barrier(0);                                         \
  } while (0)

#define MFMA16(AF, BF, ACC, OFF)                                               \
  do {                                                                         \
    __builtin_amdgcn_s_setprio(1);                                             \
    _Pragma("unroll") for (int i_ = 0; i_ < 4; i_++)                           \
        _Pragma("unroll") for (int j_ = 0; j_ < 4; j_++)                       \
            ACC[i_ + OFF][j_] = __builtin_amdgcn_mfma_f32_16x16x32_bf16(       \
                AF[i_], BF[j_], ACC[i_ + OFF][j_], 0, 0, 0);                   \
    __builtin_amdgcn_s_setprio(0);                                             \
  } while (0)

// ---------------------------------------------------------------------------
// Merged prologue: blocks 0..255 transpose/convert the 4 weight matrices
// (r9-proven LDS-tile transpose); blocks 256.. convert Xq/Xkv fp32->bf16
// (r7-proven streaming cvt at HBM floor). One launch instead of two.
// ---------------------------------------------------------------------------
__global__ void prep_cvt_kernel(const float* __restrict__ Wq,
                                const float* __restrict__ Wk,
                                const float* __restrict__ Wv,
                                const float* __restrict__ Wo,
                                bf16_t* __restrict__ wt,
                                const float* __restrict__ xq,
                                const float* __restrict__ xkv,
                                bf16_t* __restrict__ oq,
                                bf16_t* __restrict__ okv) {
  __shared__ float t[64][65];
  const int bid = blockIdx.x;
  const int tid = threadIdx.x;

  if (bid < 256) {
    // ---- weight transpose: bid -> (mat, n-tile, d-tile) ----
    const int mat = bid >> 6;
    const int rem = bid & 63;
    const int d0 = (rem & 7) * 64, n0 = (rem >> 3) * 64;
    const float* src = (mat == 0) ? Wq : (mat == 1) ? Wk : (mat == 2) ? Wv : Wo;
    const float scale = (mat == 0) ? 0.125f : 1.0f;  // 1/sqrt(64) into Wq
    const int c = tid & 63, rb = tid >> 6;
#pragma unroll
    for (int i = 0; i < 16; i++) {
      const int r = i * 4 + rb;
      t[r][c] = src[(size_t)(d0 + r) * 512 + n0 + c];
    }
    __syncthreads();
#pragma unroll
    for (int i = 0; i < 16; i++) {
      const int n = i * 4 + rb;
      wt[((size_t)mat * 512 + n0 + n) * 512 + d0 + c] =
          (bf16_t)(t[c][n] * scale);
    }
  } else {
    // ---- activation cvt: 32768 blocks, 8 elem/thread ----
    const int idx = bid - 256;
    const float* src = (idx >= 16384) ? xkv : xq;
    bf16_t* dst = (idx >= 16384) ? okv : oq;
    const size_t e = ((size_t)(idx & 16383) * 256 + tid) * 8;
    float4 a = *reinterpret_cast<const float4*>(src + e);
    float4 b = *reinterpret_cast<const float4*>(src + e + 4);
    bf16x8 o;
    o[0] = (bf16_t)a.x; o[1] = (bf16_t)a.y; o[2] = (bf16_t)a.z; o[3] = (bf16_t)a.w;
    o[4] = (bf16_t)b.x; o[5] = (bf16_t)b.y; o[6] = (bf16_t)b.z; o[7] = (bf16_t)b.w;
    *reinterpret_cast<bf16x8*>(dst + e) = o;
  }
}

// ---------------------------------------------------------------------------
// Fragment read, [256 rows][32 bf16] region (64 B rows), proven balanced
// swizzle (0 conflicts measured): LDS[row][p] = global[row][p ^ ((row>>1)&3)].
// ---------------------------------------------------------------------------
__device__ __forceinline__ bf16x8 rdfrag(const bf16_t* region, int rowbase,
                                         int lane) {
  const int fr = lane & 15;
  const int fs = (lane >> 4) ^ ((lane >> 1) & 3);
  return *reinterpret_cast<const bf16x8*>(region + (rowbase + fr) * 32 + fs * 8);
}

// ---------------------------------------------------------------------------
// 256x256 8-phase GEMM (proven r7/r13: 0 conflicts, MfmaUtil ~33%): all-bf16,
// K=512. 512 threads = 8 waves (2M x 4N), BK=64, LDS 128 KB double-buffered,
// counted vmcnt(6), both-sides swizzle, T1 XCD-bijective grid.
// NTILE n-tiles: seg=mx>>1 picks A0->C0 / A1->C1,C2 (fused QKV); NTILE=2
// uses seg 0 only (O-projection).
// ---------------------------------------------------------------------------
template <typename OT, int NTILE>
__global__ __launch_bounds__(512, 2)
void gemm256(const bf16_t* __restrict__ A0, const bf16_t* __restrict__ A1,
             const bf16_t* __restrict__ BT,
             OT* __restrict__ C0, OT* __restrict__ C1, OT* __restrict__ C2) {
  __shared__ __align__(16) bf16_t lds[65536];  // 128 KiB

  constexpr int NB = NTILE * 256;
  const int bid = blockIdx.x;
  const int swz = (bid & 7) * (NB / 8) + (bid >> 3);
  const int my = swz / NTILE;
  const int mx = swz - my * NTILE;
  const int m0 = my * 256;
  const int seg = mx >> 1;
  const int ncol0 = (mx & 1) * 256;
  const int nB0 = mx * 256;

  const bf16_t* const A = (seg == 0) ? A0 : A1;
  OT* const outp = (seg == 0) ? C0 : (seg == 1) ? C1 : C2;

  const int tid = threadIdx.x;
  const int lane = tid & 63;
  const int wid = tid >> 6;
  const int wmB = (wid >> 2) * 128;
  const int wnB = (wid & 3) * 64;

  const int sr0 = tid >> 2;
  const int sgs = (tid & 3) ^ ((sr0 >> 1) & 3);
  const bf16_t* const Agb = A + ((size_t)m0 + sr0) * 512 + sgs * 8;
  const bf16_t* const Bgb = BT + ((size_t)nB0 + sr0) * 512 + sgs * 8;

  auto stage = [&](int tile, int mat, int kh) {
    if (tile >= 8) return;
    bf16_t* reg = lds + ((tile & 1) * 4 + mat * 2 + kh) * 8192;
    const bf16_t* g0 = (mat == 0 ? Agb : Bgb) + tile * 64 + kh * 32;
    char* lp = (char*)reg + wid * 1024;
    GLOAD16(g0, lp);
    GLOAD16(g0 + (size_t)128 * 512, lp + 8192);
  };

  f32x4 acc[8][4] = {};
  bf16x8 a0[4], a1[4], a2[4], a3[4], b0[4], b2[4];

  // prologue: tile0 fully + tile1 {Bkh0, Akh0, Bkh1}  (7 half-tiles)
  stage(0, 0, 0); stage(0, 1, 0); stage(0, 0, 1); stage(0, 1, 1);
  stage(1, 1, 0); stage(1, 0, 0); stage(1, 1, 1);
  asm volatile("s_waitcnt vmcnt(6)" ::: "memory");  // tile0 landed
  __builtin_amdgcn_s_barrier();

  for (int t = 0; t < 8; ++t) {
    const int p = t & 1;
    const bf16_t* Ap0 = lds + (p * 4 + 0) * 8192;
    const bf16_t* Ap1 = lds + (p * 4 + 1) * 8192;
    const bf16_t* Bp0 = lds + (p * 4 + 2) * 8192;
    const bf16_t* Bp1 = lds + (p * 4 + 3) * 8192;

    // ph0: RD A[kh0]m0-3 + B[kh0]; ST A(t+1)kh1; MFMA tail t-1
#pragma unroll
    for (int q = 0; q < 4; q++) a0[q] = rdfrag(Ap0, wmB + q * 16, lane);
#pragma unroll
    for (int q = 0; q < 4; q++) b0[q] = rdfrag(Bp0, wnB + q * 16, lane);
    stage(t + 1, 0, 1);
    __builtin_amdgcn_s_barrier();
    WAIT_LGKM0();
    if (t > 0) MFMA16(a3, b2, acc, 4);
    __builtin_amdgcn_s_barrier();

    // ph1: RD A[kh0]m4-7; ST B(t+2)kh0; MFMA m0-3 x kh0
#pragma unroll
    for (int q = 0; q < 4; q++) a1[q] = rdfrag(Ap0, wmB + 64 + q * 16, lane);
    stage(t + 2, 1, 0);
    __builtin_amdgcn_s_barrier();
    WAIT_LGKM0();
    MFMA16(a0, b0, acc, 0);
    __builtin_amdgcn_s_barrier();

    // ph2: RD A[kh1]m0-3 + B[kh1]; ST A(t+2)kh0; MFMA m4-7 x kh0
#pragma unroll
    for (int q = 0; q < 4; q++) a2[q] = rdfrag(Ap1, wmB + q * 16, lane);
#pragma unroll
    for (int q = 0; q < 4; q++) b2[q] = rdfrag(Bp1, wnB + q * 16, lane);
    stage(t + 2, 0, 0);
    __builtin_amdgcn_s_barrier();
    WAIT_LGKM0();
    MFMA16(a1, b0, acc, 4);
    __builtin_amdgcn_s_barrier();

    // ph3: RD A[kh1]m4-7; ST B(t+2)kh1; MFMA m0-3 x kh1; vmcnt gate
#pragma unroll
    for (int q = 0; q < 4; q++) a3[q] = rdfrag(Ap1, wmB + 64 + q * 16, lane);
    stage(t + 2, 1, 1);
    __builtin_amdgcn_s_barrier();
    WAIT_LGKM0();
    MFMA16(a2, b2, acc, 0);
    if (t < 6) {
      asm volatile("s_waitcnt vmcnt(6)" ::: "memory");  // tile t+1 landed
    } else {
      asm volatile("s_waitcnt vmcnt(0)" ::: "memory");  // tail drain
    }
    __builtin_amdgcn_s_barrier();
  }

  MFMA16(a3, b2, acc, 4);  // tile7 m4-7 x kh1

  const int crow = (lane >> 4) * 4;
  const int ccol = lane & 15;
#pragma unroll
  for (int i = 0; i < 8; i++) {
#pragma unroll
    for (int j = 0; j < 4; j++) {
      const int gm = m0 + wmB + i * 16 + crow;
      const int gn = ncol0 + wnB + j * 16 + ccol;
#pragma unroll
      for (int jj = 0; jj < 4; jj++) {
        const float vv = acc[i][j][jj];
        if constexpr (std::is_same<OT, float>::value)
          outp[(size_t)(gm + jj) * 512 + gn] = vv;
        else
          outp[(size_t)(gm + jj) * 512 + gn] = (bf16_t)vv;
      }
    }
  }
}

// ---------------------------------------------------------------------------
// Attention (proven r12/r13): one block per (h, c, b), XCD-swizzled, 4 waves
// x 32 rows, T5 setprio around MFMA clusters. CLS key via VALU dot + rank-1.
// ---------------------------------------------------------------------------
__global__ __launch_bounds__(256, 3)
void attn_kernel(const bf16_t* __restrict__ q, const bf16_t* __restrict__ k,
                 const bf16_t* __restrict__ v, bf16_t* __restrict__ ctx) {
  const int bid = blockIdx.x;                      // 4096 blocks
  const int swz = (bid & 7) * 512 + (bid >> 3);    // 4096 % 8 == 0
  const int h = swz & 7;
  const int cb = swz >> 3;
  const int c = cb & 63;
  const int b = cb >> 6;

  const int tid = threadIdx.x;
  const int lane = tid & 63;
  const int w = tid >> 6;
  const int cl = lane & 15;
  const int g = lane >> 4;

  __shared__ bf16_t vT[64][136];    // V^T: [kdim][m]
  __shared__ bf16_t pL[128][136];   // normalized P (bf16)
  __shared__ float scl[128];        // cls score, then normalized cls prob
  __shared__ bf16_t kcls[64];
  __shared__ bf16_t vcls[64];

  const size_t headoff = (size_t)h * KD_;
  const size_t rowbase = (size_t)b * L_ + (size_t)c * W_;

  if (tid < 64) {
    kcls[tid] = k[(size_t)b * L_ * HK_ + headoff + tid];
    vcls[tid] = v[(size_t)b * L_ * HK_ + headoff + tid];
  }
  {
    const int m = tid >> 1;
    const int kd0 = (tid & 1) * 32;
    const bf16_t* vp = v + (rowbase + m) * HK_ + headoff + kd0;
#pragma unroll
    for (int i = 0; i < 4; i++) {
      bf16x8 t8 = *reinterpret_cast<const bf16x8*>(vp + i * 8);
#pragma unroll
      for (int j = 0; j < 8; j++) vT[kd0 + i * 8 + j][m] = t8[j];
    }
  }

  bf16x8 qf[2][2];
#pragma unroll
  for (int rt = 0; rt < 2; rt++)
#pragma unroll
    for (int kk = 0; kk < 2; kk++) {
      const size_t row = rowbase + w * 32 + rt * 16 + cl;
      qf[rt][kk] = *reinterpret_cast<const bf16x8*>(&q[row * HK_ + headoff + kk * 32 + g * 8]);
    }

  f32x4 sacc[2][8] = {};
#pragma unroll
  for (int ct = 0; ct < 8; ct++) {
    bf16x8 kf[2];
#pragma unroll
    for (int kk = 0; kk < 2; kk++) {
      const size_t rowm = rowbase + ct * 16 + cl;
      kf[kk] = *reinterpret_cast<const bf16x8*>(&k[rowm * HK_ + headoff + kk * 32 + g * 8]);
    }
    __builtin_amdgcn_s_setprio(1);
#pragma unroll
    for (int rt = 0; rt < 2; rt++)
#pragma unroll
      for (int kk = 0; kk < 2; kk++)
        sacc[rt][ct] = __builtin_amdgcn_mfma_f32_16x16x32_bf16(qf[rt][kk], kf[kk], sacc[rt][ct], 0, 0, 0);
    __builtin_amdgcn_s_setprio(0);
  }

  __syncthreads();

#pragma unroll
  for (int rt = 0; rt < 2; rt++) {
    float part = 0.f;
#pragma unroll
    for (int kk = 0; kk < 2; kk++)
#pragma unroll
      for (int j = 0; j < 8; j++)
        part += (float)qf[rt][kk][j] * (float)kcls[kk * 32 + g * 8 + j];
    part += __shfl_xor(part, 16);
    part += __shfl_xor(part, 32);
    if (g == 0) scl[w * 32 + rt * 16 + cl] = part;
  }

  float invd[2][4];
#pragma unroll
  for (int rt = 0; rt < 2; rt++) {
#pragma unroll
    for (int jj = 0; jj < 4; jj++) {
      float mx = sacc[rt][0][jj];
#pragma unroll
      for (int ct = 1; ct < 8; ct++) mx = fmaxf(mx, sacc[rt][ct][jj]);
#pragma unroll
      for (int d = 1; d < 16; d <<= 1) mx = fmaxf(mx, __shfl_xor(mx, d));
      const float sc = scl[w * 32 + rt * 16 + g * 4 + jj];
      mx = fmaxf(mx, sc);
      float sum = 0.f;
#pragma unroll
      for (int ct = 0; ct < 8; ct++) {
        const float e = __expf(sacc[rt][ct][jj] - mx);
        sacc[rt][ct][jj] = e;
        sum += e;
      }
#pragma unroll
      for (int d = 1; d < 16; d <<= 1) sum += __shfl_xor(sum, d);
      const float pc = __expf(sc - mx);
      sum += pc;
      const float inv = 1.0f / sum;
      invd[rt][jj] = inv;
      if (cl == 0) scl[w * 32 + rt * 16 + g * 4 + jj] = pc * inv;
    }
  }

#pragma unroll
  for (int rt = 0; rt < 2; rt++)
#pragma unroll
    for (int jj = 0; jj < 4; jj++) {
      const int row = w * 32 + rt * 16 + g * 4 + jj;
#pragma unroll
      for (int ct = 0; ct < 8; ct++)
        pL[row][ct * 16 + cl] = (bf16_t)(sacc[rt][ct][jj] * invd[rt][jj]);
    }
  __syncthreads();

  f32x4 cacc[2][4] = {};
#pragma unroll
  for (int kk = 0; kk < 4; kk++) {
    bf16x8 vf[4];
#pragma unroll
    for (int c2 = 0; c2 < 4; c2++)
      vf[c2] = *reinterpret_cast<const bf16x8*>(&vT[c2 * 16 + cl][kk * 32 + g * 8]);
    __builtin_amdgcn_s_setprio(1);
#pragma unroll
    for (int rt = 0; rt < 2; rt++) {
      const bf16x8 pf = *reinterpret_cast<const bf16x8*>(&pL[w * 32 + rt * 16 + cl][kk * 32 + g * 8]);
#pragma unroll
      for (int c2 = 0; c2 < 4; c2++)
        cacc[rt][c2] = __builtin_amdgcn_mfma_f32_16x16x32_bf16(pf, vf[c2], cacc[rt][c2], 0, 0, 0);
    }
    __builtin_amdgcn_s_setprio(0);
  }

#pragma unroll
  for (int rt = 0; rt < 2; rt++)
#pragma unroll
    for (int c2 = 0; c2 < 4; c2++)
#pragma unroll
      for (int jj = 0; jj < 4; jj++) {
        const int row = w * 32 + rt * 16 + g * 4 + jj;
        const int kd = c2 * 16 + cl;
        const float val = cacc[rt][c2][jj] + scl[row] * (float)vcls[kd];
        ctx[(rowbase + row) * HK_ + headoff + kd] = (bf16_t)val;
      }
}

// ---------------------------------------------------------------------------
extern "C" void kernel_launch(void* const* d_in, const int* in_sizes, int n_in,
                              void* d_out, int out_size, void* d_ws, size_t ws_size,
                              hipStream_t stream) {
  const float* Xq = (const float*)d_in[0];
  const float* Xkv = (const float*)d_in[1];
  const float* Wq = (const float*)d_in[2];
  const float* Wk = (const float*)d_in[3];
  const float* Wv = (const float*)d_in[4];
  const float* Wo = (const float*)d_in[5];
  float* out = (float*)d_out;

  char* ws = (char*)d_ws;
  bf16_t* wT = (bf16_t*)ws;                                   // 4 x 512 x 512 bf16
  size_t off = (size_t)4 * 512 * 512 * sizeof(bf16_t);        // 2 MiB
  bf16_t* xqb  = (bf16_t*)(ws + off); off += (size_t)M_ * D_ * 2;
  bf16_t* xkvb = (bf16_t*)(ws + off); off += (size_t)M_ * D_ * 2;
  bf16_t* qb = (bf16_t*)(ws + off); off += (size_t)M_ * HK_ * 2;
  bf16_t* kb = (bf16_t*)(ws + off); off += (size_t)M_ * HK_ * 2;
  bf16_t* vb = (bf16_t*)(ws + off);
  bf16_t* ctxb = xqb;  // xqb dead after QKV projection; reuse for ctx

  bf16_t* wTqkv = wT;                      // q|k|v stacked: 1536 rows
  bf16_t* wTo = wT + (size_t)3 * 512 * 512;

  // Merged prologue: weight transpose (256 blocks) + activation cvt (32768)
  prep_cvt_kernel<<<dim3(256 + 32768), 256, 0, stream>>>(
      Wq, Wk, Wv, Wo, wT, Xq, Xkv, xqb, xkvb);

  // Fused Q+K+V projections: 6 n-tiles (2 per output) x 256 m-panels
  gemm256<bf16_t, 6><<<dim3(6 * (M_ / 256)), 512, 0, stream>>>(
      xqb, xkvb, wTqkv, qb, kb, vb);

  attn_kernel<<<dim3(H_ * C_ * B_), 256, 0, stream>>>(qb, kb, vb, ctxb);

  // Output projection: ctx [M][512] bf16 @ WoT -> out fp32
  gemm256<float, 2><<<dim3(2 * (M_ / 256)), 512, 0, stream>>>(
      ctxb, ctxb, wTo, out, out, out);
}